// Round 16
// baseline (2516.629 us; speedup 1.0000x reference)
//
#include <hip/hip_runtime.h>

typedef float v2f __attribute__((ext_vector_type(2)));
typedef unsigned uv2 __attribute__((ext_vector_type(2)));

constexpr int NX = 32, NU = 16, NF = 512;
constexpr int SEQ = 2048;
constexpr int NT = 512;           // 8 waves/block; 1 row/block; 1 feature/thread
constexpr float SC  = 2.88539008177792681f;  // 2/ln2: tanh(a) = 1 - 2/(exp2(SC*a)+1)
constexpr float TSC = 0.01f;

// DPP partner read (VALU pipe). Direction-proof controls only:
// 0xB1 quad_perm xor1 | 0x4E quad_perm xor2 | 0x128 row_ror:8 (= xor8 both directions)
template<int CTRL>
__device__ __forceinline__ float dpp_mov(float v) {
    return __int_as_float(__builtin_amdgcn_update_dpp(0, __float_as_int(v), CTRL, 0xF, 0xF, true));
}
// gfx950 permlane swaps (VALU pipe): v[l] + v[l^16] / v[l^32]
__device__ __forceinline__ float sum16(float v) {
    uv2 r = __builtin_amdgcn_permlane16_swap(__float_as_uint(v), __float_as_uint(v), false, false);
    return __uint_as_float(r.x) + __uint_as_float(r.y);
}
__device__ __forceinline__ float sum32(float v) {
    uv2 r = __builtin_amdgcn_permlane32_swap(__float_as_uint(v), __float_as_uint(v), false, false);
    return __uint_as_float(r.x) + __uint_as_float(r.y);
}

__device__ __forceinline__ float tanh4(float y) {       // y pre-scaled by SC
    const float e = __builtin_amdgcn_exp2f(y);
    const float r = __builtin_amdgcn_rcpf(e + 1.f);
    return fmaf(-2.f, r, 1.f);
}

// LDS-only barrier: no vmcnt drain (out-stores / u-prefetch stay in flight)
__device__ __forceinline__ void bar_lds() {
    asm volatile("s_waitcnt lgkmcnt(0)" ::: "memory");
    __builtin_amdgcn_sched_barrier(0);
    __builtin_amdgcn_s_barrier();
    __builtin_amdgcn_sched_barrier(0);
    asm volatile("" ::: "memory");
}

__global__ __launch_bounds__(NT)
__attribute__((amdgpu_waves_per_eu(4, 4)))   // 128-reg budget -> 2 blocks/CU = 16 waves/CU
void fes_kernel(const float* __restrict__ x0, const float* __restrict__ ug,
                const float* __restrict__ W1, const float* __restrict__ b1,
                const float* __restrict__ W2, const float* __restrict__ b2,
                float* __restrict__ out)
{
    // [buf][j][16 slots + 4 pad]: row = 80 B (16B-aligned); 4-way bank aliasing max
    __shared__ __align__(16) float part[2][NX][20];

    const int tid = threadIdx.x, row = blockIdx.x;
    const int l = tid & 63, w = tid >> 6;           // 8 waves

    // lane -> owned output j (XOR-linear): pi(1)=16, pi(2)=8, pi(8)=4, pi(16)=2, pi(32)=1, pi(4)=0
    const int pi = ((l & 1) << 4) | (((l >> 1) & 1) << 3) | (((l >> 3) & 1) << 2)
                 | (((l >> 4) & 1) << 1) | ((l >> 5) & 1);
    const int slot = 2 * w + ((l >> 2) & 1);        // 8 waves x 2 cosets = 16 partials/j
    const bool store_lane = (w == 0) && ((l & 4) == 0);

    const int f0 = tid;                             // this thread's single feature

    // ---- persistent registers (80 weight floats) -------------------------
    // G1 x-part weights, canonical scalar order (x operand comes from SGPRs)
    float w1x[32];
#pragma unroll
    for (int k = 0; k < 32; ++k) w1x[k] = SC * W1[k * NF + f0];
    // G1 u-part weights as k-parity pairs (u stays in VGPRs)
    v2f wu[8];
#pragma unroll
    for (int p = 0; p < 8; ++p) {
        const int k = NX + 2 * p;
        wu[p] = v2f{SC * W1[k * NF + f0], SC * W1[(k + 1) * NF + f0]};
    }
    const float b1r = SC * b1[f0];

    // G2 weights, pi-domain: position p holds j = p ^ pi
    v2f wc[16];
#pragma unroll
    for (int m = 0; m < 16; ++m)
        wc[m] = v2f{TSC * W2[f0 * NX + ((2 * m) ^ pi)],
                    TSC * W2[f0 * NX + ((2 * m + 1) ^ pi)]};
    const float bb = TSC * b2[pi];
    float xr = x0[row * NX + pi];                   // lane-resident state element

    // uniform x state (SGPRs), canonical order
    float xu[32];
#pragma unroll
    for (int k = 0; k < 32; ++k) xu[k] = x0[row * NX + k];

    const float* ug_row  = ug  + (size_t)row * SEQ * NU;
    float*       out_row = out + (size_t)row * SEQ * NX;

    float4 u0 = *(const float4*)(ug_row + 0);
    float4 u1 = *(const float4*)(ug_row + 4);
    float4 u2 = *(const float4*)(ug_row + 8);
    float4 u3 = *(const float4*)(ug_row + 12);

#pragma unroll 1
    for (int t = 0; t < SEQ; ++t) {
        // ---- G1 x-part: scalar fma with SGPR x operand (no LDS) ----------
        float a0 = b1r, a1 = 0.f, a2 = 0.f, a3 = 0.f;
#pragma unroll
        for (int k = 0; k < 32; k += 4) {
            a0 = fmaf(w1x[k],     xu[k],     a0);
            a1 = fmaf(w1x[k + 1], xu[k + 1], a1);
            a2 = fmaf(w1x[k + 2], xu[k + 2], a2);
            a3 = fmaf(w1x[k + 3], xu[k + 3], a3);
        }
        // ---- G1 u-part: pk pairs ----------------------------------------
        v2f ua = {0.f, 0.f};
#define UPAIR(uv, p)                                                        \
        { const v2f lo = {uv.x, uv.y}, hi = {uv.z, uv.w};                   \
          ua += wu[p] * lo;  ua += wu[p + 1] * hi; }
        UPAIR(u0, 0) UPAIR(u1, 2) UPAIR(u2, 4) UPAIR(u3, 6)
#undef UPAIR
        // prefetch next u (no vmcnt drain at barrier -> true overlap)
        {
            const int tn = (t + 1 < SEQ) ? t + 1 : SEQ - 1;
            const float* un = ug_row + (size_t)tn * NU;
            u0 = *(const float4*)(un + 0);
            u1 = *(const float4*)(un + 4);
            u2 = *(const float4*)(un + 8);
            u3 = *(const float4*)(un + 12);
        }
        const float h = tanh4(((a0 + a1) + (a2 + a3)) + (ua.x + ua.y));

        // ---- G2: pi-domain partials for this feature (16 pk mul) ---------
        const v2f hv = {h, h};
        v2f q[16];
#pragma unroll
        for (int m = 0; m < 16; ++m) q[m] = hv * wc[m];

        // ---- in-wave reduce-scatter (direction-proof ops only) -----------
#pragma unroll
        for (int m = 0; m < 8; ++m) {                 // d=1 (j-bit 16)
            q[m].x += dpp_mov<0xB1>(q[m + 8].x);
            q[m].y += dpp_mov<0xB1>(q[m + 8].y);
        }
#pragma unroll
        for (int m = 0; m < 4; ++m) {                 // d=2 (j-bit 8)
            q[m].x += dpp_mov<0x4E>(q[m + 4].x);
            q[m].y += dpp_mov<0x4E>(q[m + 4].y);
        }
#pragma unroll
        for (int m = 0; m < 2; ++m) {                 // d=8 (j-bit 4)
            q[m].x += dpp_mov<0x128>(q[m + 2].x);
            q[m].y += dpp_mov<0x128>(q[m + 2].y);
        }
        // d=16 (j-bit 2), d=32 (j-bit 1): partner = sum - self
        const float S0 = q[0].x + (sum16(q[1].x) - q[1].x);
        const float S1 = q[0].y + (sum16(q[1].y) - q[1].y);
        const float S  = S0 + (sum32(S1) - S1);
        // d=4 not folded: both coset lanes write their partial (16 slots/j)

        // ---- cross-wave combine: 1 write, 1 barrier, 4 b128 reads --------
        part[t & 1][pi][slot] = S;
        bar_lds();
        const float4 pa = *(const float4*)&part[t & 1][pi][0];
        const float4 pb = *(const float4*)&part[t & 1][pi][4];
        const float4 pc = *(const float4*)&part[t & 1][pi][8];
        const float4 pd = *(const float4*)&part[t & 1][pi][12];
        const float dx = ((((pa.x + pa.y) + (pa.z + pa.w))
                         + ((pb.x + pb.y) + (pb.z + pb.w)))
                        + (((pc.x + pc.y) + (pc.z + pc.w))
                         + ((pd.x + pd.y) + (pd.z + pd.w)))) + bb;
        const float xn = xr + dx;
        xr = xn;
        if (store_lane) out_row[(size_t)t * NX + pi] = xn;

        // ---- broadcast state to SGPRs: 32 compile-time readlanes ---------
#pragma unroll
        for (int k = 0; k < 32; ++k) {
            const int L = ((k >> 4) & 1) | (((k >> 3) & 1) << 1) | (((k >> 2) & 1) << 3)
                        | (((k >> 1) & 1) << 4) | ((k & 1) << 5);   // pi(L)=k (L bit2=0)
            xu[k] = __int_as_float(__builtin_amdgcn_readlane(__float_as_int(xn), L));
        }
    }
}

extern "C" void kernel_launch(void* const* d_in, const int* in_sizes, int n_in,
                              void* d_out, int out_size, void* d_ws, size_t ws_size,
                              hipStream_t stream) {
    const float* x0 = (const float*)d_in[0];
    const float* ug = (const float*)d_in[1];
    const float* W1 = (const float*)d_in[2];
    const float* b1 = (const float*)d_in[3];
    const float* W2 = (const float*)d_in[4];
    const float* b2 = (const float*)d_in[5];
    float* out = (float*)d_out;

    fes_kernel<<<dim3(512), dim3(NT), 0, stream>>>(x0, ug, W1, b1, W2, b2, out);
}

// Round 17
// 1857.106 us; speedup vs baseline: 1.3551x; 1.3551x over previous
//
#include <hip/hip_runtime.h>

typedef float v2f __attribute__((ext_vector_type(2)));
typedef unsigned uv2 __attribute__((ext_vector_type(2)));

constexpr int NX = 32, NU = 16, NF = 512;
constexpr int SEQ = 2048;
constexpr int NT = 256;           // 1 row/block; 2 features/thread end-to-end
constexpr float SC  = 2.88539008177792681f;  // 2/ln2: tanh(a) = 1 - 2/(exp2(SC*a)+1)
constexpr float TSC = 0.01f;

// DPP partner read (VALU pipe). Direction-proof controls only:
// 0xB1 quad_perm xor1 | 0x4E quad_perm xor2 | 0x128 row_ror:8 (= xor8 both directions)
template<int CTRL>
__device__ __forceinline__ float dpp_mov(float v) {
    return __int_as_float(__builtin_amdgcn_update_dpp(0, __float_as_int(v), CTRL, 0xF, 0xF, true));
}
// gfx950 permlane swaps (VALU pipe): v[l] + v[l^16] / v[l^32]
__device__ __forceinline__ float sum16(float v) {
    uv2 r = __builtin_amdgcn_permlane16_swap(__float_as_uint(v), __float_as_uint(v), false, false);
    return __uint_as_float(r.x) + __uint_as_float(r.y);
}
__device__ __forceinline__ float sum32(float v) {
    uv2 r = __builtin_amdgcn_permlane32_swap(__float_as_uint(v), __float_as_uint(v), false, false);
    return __uint_as_float(r.x) + __uint_as_float(r.y);
}

__device__ __forceinline__ float tanh4(float y) {       // y pre-scaled by SC
    const float e = __builtin_amdgcn_exp2f(y);
    const float r = __builtin_amdgcn_rcpf(e + 1.f);
    return fmaf(-2.f, r, 1.f);
}

// LDS barrier: orders MEMORY ops only; register VALU may cross (no sched_barrier).
__device__ __forceinline__ void bar_lds() {
    asm volatile("s_waitcnt lgkmcnt(0)" ::: "memory");
    __builtin_amdgcn_s_barrier();
    asm volatile("" ::: "memory");
}

__global__ __launch_bounds__(NT)
__attribute__((amdgpu_waves_per_eu(2, 2)))   // 256-reg budget, 2 waves/SIMD
void fes_kernel(const float* __restrict__ x0, const float* __restrict__ ug,
                const float* __restrict__ W1, const float* __restrict__ b1,
                const float* __restrict__ W2, const float* __restrict__ b2,
                float* __restrict__ out)
{
    __shared__ __align__(16) float xs_w[4][NX];     // per-wave private state copies
    __shared__ float part[2][8][33];                // ping-pong partials; stride 33: conflict-free

    const int tid = threadIdx.x, row = blockIdx.x;
    const int l = tid & 63, w = tid >> 6;

    // lane -> owned output j (XOR-linear): pi(1)=16, pi(2)=8, pi(8)=4, pi(16)=2, pi(32)=1, pi(4)=0
    const int pi = ((l & 1) << 4) | (((l >> 1) & 1) << 3) | (((l >> 3) & 1) << 2)
                 | (((l >> 4) & 1) << 1) | ((l >> 5) & 1);
    const int slot = 2 * w + ((l >> 2) & 1);        // 8 coset-partials per j
    const bool jown = (l & 4) == 0;
    const bool store_lane = (w == 0) && jown;

    const int f0 = 2 * tid, f1 = f0 + 1;            // this thread's two features

    // ---- persistent registers (R12-proven maps) --------------------------
    v2f wkA[24], wkB[24];                           // G1 weights, k-parity pairs (k=0..47)
#pragma unroll
    for (int p = 0; p < 24; ++p) {
        wkA[p] = v2f{SC * W1[(2 * p) * NF + f0], SC * W1[(2 * p + 1) * NF + f0]};
        wkB[p] = v2f{SC * W1[(2 * p) * NF + f1], SC * W1[(2 * p + 1) * NF + f1]};
    }
    const float b1A = SC * b1[f0], b1B = SC * b1[f1];

    v2f wcA[16], wcB[16];                           // G2 weights, pi-domain
#pragma unroll
    for (int m = 0; m < 16; ++m) {
        wcA[m] = v2f{TSC * W2[f0 * NX + ((2 * m) ^ pi)], TSC * W2[f0 * NX + ((2 * m + 1) ^ pi)]};
        wcB[m] = v2f{TSC * W2[f1 * NX + ((2 * m) ^ pi)], TSC * W2[f1 * NX + ((2 * m + 1) ^ pi)]};
    }
    const float bb = TSC * b2[pi];
    float xr = x0[row * NX + pi];                   // lane-resident state element

    const float* ug_row  = ug  + (size_t)row * SEQ * NU;
    float*       out_row = out + (size_t)row * SEQ * NX;

    if (jown) xs_w[w][pi] = xr;                     // wave-private: in-wave ordering suffices
    const float4* xsr = (const float4*)xs_w[w];

    // ---- u software pipeline ---------------------------------------------
    // ud = u-dot for step t (computed one step ahead); u regs hold u(t+1)
    v2f udA, udB;
    float4 u0, u1, u2, u3;
    {
        const float4 a0 = *(const float4*)(ug_row + 0);
        const float4 a1 = *(const float4*)(ug_row + 4);
        const float4 a2 = *(const float4*)(ug_row + 8);
        const float4 a3 = *(const float4*)(ug_row + 12);
        udA = v2f{0.f, 0.f}; udB = v2f{0.f, 0.f};
#define UD0(uv, p)                                                          \
        { const v2f lo = {uv.x, uv.y}, hi = {uv.z, uv.w};                   \
          udA += wkA[p] * lo;  udA += wkA[p + 1] * hi;                      \
          udB += wkB[p] * lo;  udB += wkB[p + 1] * hi; }
        UD0(a0, 16) UD0(a1, 18) UD0(a2, 20) UD0(a3, 22)
#undef UD0
        const float* un = ug_row + NU;              // u(1)
        u0 = *(const float4*)(un + 0);
        u1 = *(const float4*)(un + 4);
        u2 = *(const float4*)(un + 8);
        u3 = *(const float4*)(un + 12);
    }

#pragma unroll 1
    for (int t = 0; t < SEQ; ++t) {
        // ---- G1 x-part (8 uniform b128) + pipelined u-dot ----------------
        v2f aA0 = {b1A, 0.f}, aA1 = {0.f, 0.f};
        v2f aB0 = {b1B, 0.f}, aB1 = {0.f, 0.f};
#pragma unroll
        for (int s = 0; s < 8; ++s) {
            const float4 iv = xsr[s];               // wave-uniform broadcast
            const v2f lo = {iv.x, iv.y}, hi = {iv.z, iv.w};
            aA0 += wkA[2 * s] * lo;  aA1 += wkA[2 * s + 1] * hi;
            aB0 += wkB[2 * s] * lo;  aB1 += wkB[2 * s + 1] * hi;
        }
        const float h0 = tanh4((aA0.x + aA0.y) + (aA1.x + aA1.y) + (udA.x + udA.y));
        const float h1 = tanh4((aB0.x + aB0.y) + (aB1.x + aB1.y) + (udB.x + udB.y));

        // ---- G2: in-register, pi-permuted (32 pk-fma) --------------------
        const v2f h0v = {h0, h0}, h1v = {h1, h1};
        v2f q[16];
#pragma unroll
        for (int m = 0; m < 16; ++m)
            q[m] = h0v * wcA[m] + h1v * wcB[m];

        // ---- in-wave reduce-scatter (direction-proof ops only) -----------
#pragma unroll
        for (int m = 0; m < 8; ++m) {                 // d=1 (j-bit 16)
            q[m].x += dpp_mov<0xB1>(q[m + 8].x);
            q[m].y += dpp_mov<0xB1>(q[m + 8].y);
        }
#pragma unroll
        for (int m = 0; m < 4; ++m) {                 // d=2 (j-bit 8)
            q[m].x += dpp_mov<0x4E>(q[m + 4].x);
            q[m].y += dpp_mov<0x4E>(q[m + 4].y);
        }
#pragma unroll
        for (int m = 0; m < 2; ++m) {                 // d=8 (j-bit 4)
            q[m].x += dpp_mov<0x128>(q[m + 2].x);
            q[m].y += dpp_mov<0x128>(q[m + 2].y);
        }
        const float S0 = q[0].x + (sum16(q[1].x) - q[1].x);   // d=16 (j-bit 2)
        const float S1 = q[0].y + (sum16(q[1].y) - q[1].y);
        const float S  = S0 + (sum32(S1) - S1);               // d=32 (j-bit 1)
        // d=4 not folded: both coset lanes write their partial (8 slots/j)

        // ---- part write, barrier -----------------------------------------
        part[t & 1][slot][pi] = S;
        bar_lds();

        // ---- post-barrier shadow: next step's u-dot (independent VALU) ---
        udA = v2f{0.f, 0.f}; udB = v2f{0.f, 0.f};
#define UDN(uv, p)                                                          \
        { const v2f lo = {uv.x, uv.y}, hi = {uv.z, uv.w};                   \
          udA += wkA[p] * lo;  udA += wkA[p + 1] * hi;                      \
          udB += wkB[p] * lo;  udB += wkB[p + 1] * hi; }
        UDN(u0, 16) UDN(u1, 18) UDN(u2, 20) UDN(u3, 22)
#undef UDN
        {   // prefetch u(t+2) into u regs (retires during next step)
            const int tn = (t + 2 < SEQ) ? t + 2 : SEQ - 1;
            const float* un = ug_row + (size_t)tn * NU;
            u0 = *(const float4*)(un + 0);
            u1 = *(const float4*)(un + 4);
            u2 = *(const float4*)(un + 8);
            u3 = *(const float4*)(un + 12);
        }

        // ---- combine: 8 b32 reads (stride 33, conflict-free) -------------
        const float* pb = &part[t & 1][0][pi];
        const float p0 = pb[0],   p1 = pb[33],  p2 = pb[66],  p3 = pb[99];
        const float p4 = pb[132], p5 = pb[165], p6 = pb[198], p7 = pb[231];
        const float dx = (((p0 + p1) + (p2 + p3)) + ((p4 + p5) + (p6 + p7))) + bb;
        const float xn = xr + dx;
        xr = xn;
        if (store_lane) out_row[(size_t)t * NX + pi] = xn;   // retires lazily
        if (jown) xs_w[w][pi] = xn;                 // own wave's copy (lgkm-ordered)
    }
}

extern "C" void kernel_launch(void* const* d_in, const int* in_sizes, int n_in,
                              void* d_out, int out_size, void* d_ws, size_t ws_size,
                              hipStream_t stream) {
    const float* x0 = (const float*)d_in[0];
    const float* ug = (const float*)d_in[1];
    const float* W1 = (const float*)d_in[2];
    const float* b1 = (const float*)d_in[3];
    const float* W2 = (const float*)d_in[4];
    const float* b2 = (const float*)d_in[5];
    float* out = (float*)d_out;

    fes_kernel<<<dim3(512), dim3(NT), 0, stream>>>(x0, ug, W1, b1, W2, b2, out);
}